// Round 2
// baseline (4723.617 us; speedup 1.0000x reference)
//
#include <hip/hip_runtime.h>
#include <cmath>

// Problem constants
#define B_   128
#define C_   9
#define N_   2048
#define D_   192
#define H_   384
#define NC_  18

// ---------------------------------------------------------------------------
// conv1d(C->D, k=3, pad=1) + transpose to [BC,N,D] + pos_embed
// grid (N/64, BC), block 192 (one thread per output channel d)
// x is pre-offset to the chunk: x[(b*C + c)*N + n]
// ---------------------------------------------------------------------------
__global__ __launch_bounds__(192) void conv_k(
    const float* __restrict__ x, const float* __restrict__ w,
    const float* __restrict__ cb, const float* __restrict__ pos,
    float* __restrict__ h)
{
    const int n0 = blockIdx.x * 64;
    const int b  = blockIdx.y;
    const int d  = threadIdx.x;

    __shared__ float xs[C_][66];
    for (int e = threadIdx.x; e < C_ * 66; e += 192) {
        int c = e / 66, i = e % 66;
        int n = n0 - 1 + i;
        xs[c][i] = (n >= 0 && n < N_) ? x[((size_t)b * C_ + c) * N_ + n] : 0.f;
    }

    float wr[C_][3];
#pragma unroll
    for (int c = 0; c < C_; ++c)
#pragma unroll
        for (int t = 0; t < 3; ++t)
            wr[c][t] = w[(d * C_ + c) * 3 + t];
    const float bias = cb[d];
    __syncthreads();

    for (int i = 0; i < 64; ++i) {
        int n = n0 + i;
        float acc = bias + pos[(size_t)n * D_ + d];
#pragma unroll
        for (int c = 0; c < C_; ++c)
#pragma unroll
            for (int t = 0; t < 3; ++t)
                acc += xs[c][i + t] * wr[c][t];
        h[((size_t)b * N_ + n) * D_ + d] = acc;
    }
}

// ---------------------------------------------------------------------------
// LayerNorm stats: one wave (64 lanes) per row of 192
// ---------------------------------------------------------------------------
__global__ __launch_bounds__(256) void lnstats_k(
    const float* __restrict__ h, float* __restrict__ mean, float* __restrict__ rstd)
{
    const int wid = threadIdx.x >> 6, lane = threadIdx.x & 63;
    const int row = blockIdx.x * 4 + wid;
    const float* hr = h + (size_t)row * D_;
    float s = 0.f, q = 0.f;
#pragma unroll
    for (int i = 0; i < 3; ++i) { float v = hr[lane + i * 64]; s += v; q += v * v; }
#pragma unroll
    for (int o = 32; o > 0; o >>= 1) { s += __shfl_xor(s, o); q += __shfl_xor(q, o); }
    if (lane == 0) {
        float m = s * (1.f / D_);
        float var = q * (1.f / D_) - m * m;
        mean[row] = m;
        rstd[row] = rsqrtf(var + 1e-5f);
    }
}

// ---------------------------------------------------------------------------
// Generic tiled SGEMM: C[m,n] = sum_k A'[m,k] * W[n,k]   (W row-major [NW,K])
// A' = optional fused LayerNorm of A. 64x64 tile, BK=16, 256 thr, 4x4 micro.
// EPI: 0 = qkv split (relu on q,k) -> o0,o1,o2
//      1 = gelu -> o0 (ld = ldo)
//      2 = hacc += acc + bias      (mlp2 residual)
//      3 = hacc += acc*invden[b] + bias  (attention residual, W batched per 2048 rows)
// ---------------------------------------------------------------------------
template <int EPI, bool LNA>
__global__ __launch_bounds__(256) void gemm_k(
    const float* __restrict__ A, const float* __restrict__ W, int K,
    const float* __restrict__ lng, const float* __restrict__ lnb,
    const float* __restrict__ mean, const float* __restrict__ rstd,
    const float* __restrict__ bias, const float* __restrict__ invden,
    float* __restrict__ o0, float* __restrict__ o1, float* __restrict__ o2,
    float* __restrict__ hacc, int ldo)
{
    __shared__ float As[16][68];
    __shared__ float Ws[16][68];

    const int tid = threadIdx.x;
    const int tx = tid & 15, ty = tid >> 4;
    const int m0 = blockIdx.x * 64;
    const int n0 = blockIdx.y * 64;
    const int batch = m0 >> 11;            // chunk-local batch (rows/2048), EPI==3
    const float* Wp = W;
    if (EPI == 3) Wp += (size_t)batch * D_ * D_;

    const int lm = tid >> 2;               // 0..63
    const int lk = (tid & 3) * 4;          // 0,4,8,12
    const int arow = m0 + lm;
    float mu = 0.f, rs = 1.f;
    if (LNA) { mu = mean[arow]; rs = rstd[arow]; }

    float acc[4][4] = {};

    for (int k0 = 0; k0 < K; k0 += 16) {
        float4 av = *(const float4*)(A + (size_t)arow * K + k0 + lk);
        if (LNA) {
            float4 g4 = *(const float4*)(lng + k0 + lk);
            float4 b4 = *(const float4*)(lnb + k0 + lk);
            av.x = (av.x - mu) * rs * g4.x + b4.x;
            av.y = (av.y - mu) * rs * g4.y + b4.y;
            av.z = (av.z - mu) * rs * g4.z + b4.z;
            av.w = (av.w - mu) * rs * g4.w + b4.w;
        }
        As[lk + 0][lm] = av.x; As[lk + 1][lm] = av.y;
        As[lk + 2][lm] = av.z; As[lk + 3][lm] = av.w;

        float4 wv = *(const float4*)(Wp + (size_t)(n0 + lm) * K + k0 + lk);
        Ws[lk + 0][lm] = wv.x; Ws[lk + 1][lm] = wv.y;
        Ws[lk + 2][lm] = wv.z; Ws[lk + 3][lm] = wv.w;
        __syncthreads();

#pragma unroll
        for (int kk = 0; kk < 16; ++kk) {
            float4 a4 = *(const float4*)&As[kk][ty * 4];
            float4 w4 = *(const float4*)&Ws[kk][tx * 4];
            float a[4] = {a4.x, a4.y, a4.z, a4.w};
            float w[4] = {w4.x, w4.y, w4.z, w4.w};
#pragma unroll
            for (int i = 0; i < 4; ++i)
#pragma unroll
                for (int j = 0; j < 4; ++j)
                    acc[i][j] += a[i] * w[j];
        }
        __syncthreads();
    }

    const int row_base = m0 + ty * 4;
    const int col_base = n0 + tx * 4;

    if (EPI == 0) {
        const int region = blockIdx.y / 3;               // 0:q 1:k 2:v
        float* dst = (region == 0) ? o0 : (region == 1 ? o1 : o2);
        const int cb0 = col_base - region * D_;
#pragma unroll
        for (int i = 0; i < 4; ++i) {
            int row = row_base + i;
            float4 vv;
            float t[4];
#pragma unroll
            for (int j = 0; j < 4; ++j) {
                float v = acc[i][j] + bias[col_base + j];
                if (region < 2) v = fmaxf(v, 0.f);
                t[j] = v;
            }
            vv.x = t[0]; vv.y = t[1]; vv.z = t[2]; vv.w = t[3];
            *(float4*)(dst + (size_t)row * D_ + cb0) = vv;
        }
    } else if (EPI == 1) {
#pragma unroll
        for (int i = 0; i < 4; ++i) {
            int row = row_base + i;
            float4 vv;
            float t[4];
#pragma unroll
            for (int j = 0; j < 4; ++j) {
                float v = acc[i][j] + bias[col_base + j];
                t[j] = 0.5f * v * (1.f + erff(v * 0.70710678118654752f));
            }
            vv.x = t[0]; vv.y = t[1]; vv.z = t[2]; vv.w = t[3];
            *(float4*)(o0 + (size_t)row * ldo + col_base) = vv;
        }
    } else if (EPI == 2) {
#pragma unroll
        for (int i = 0; i < 4; ++i) {
            int row = row_base + i;
            float4 hv = *(float4*)(hacc + (size_t)row * D_ + col_base);
            hv.x += acc[i][0] + bias[col_base + 0];
            hv.y += acc[i][1] + bias[col_base + 1];
            hv.z += acc[i][2] + bias[col_base + 2];
            hv.w += acc[i][3] + bias[col_base + 3];
            *(float4*)(hacc + (size_t)row * D_ + col_base) = hv;
        }
    } else if (EPI == 3) {
        const float s = invden[batch];
#pragma unroll
        for (int i = 0; i < 4; ++i) {
            int row = row_base + i;
            float4 hv = *(float4*)(hacc + (size_t)row * D_ + col_base);
            hv.x += acc[i][0] * s + bias[col_base + 0];
            hv.y += acc[i][1] * s + bias[col_base + 1];
            hv.z += acc[i][2] * s + bias[col_base + 2];
            hv.w += acc[i][3] * s + bias[col_base + 3];
            *(float4*)(hacc + (size_t)row * D_ + col_base) = hv;
        }
    }
}

// ---------------------------------------------------------------------------
// kv[b,d,e] = sum_n k[b,n,d] * v[b,n,e]   (batched A^T B, K = N_)
// grid (3,3,BC), 64x64 tile
// ---------------------------------------------------------------------------
__global__ __launch_bounds__(256) void kv_k(
    const float* __restrict__ kq, const float* __restrict__ vq, float* __restrict__ kv)
{
    __shared__ float Ks[16][68];
    __shared__ float Vs[16][68];
    const int tid = threadIdx.x;
    const int tx = tid & 15, ty = tid >> 4;
    const int d0 = blockIdx.x * 64, e0 = blockIdx.y * 64, b = blockIdx.z;
    const float* kb = kq + (size_t)b * N_ * D_;
    const float* vb = vq + (size_t)b * N_ * D_;

    const int lkk = tid >> 4;           // 0..15 (n within K-tile)
    const int lmm = (tid & 15) * 4;     // 0..60

    float acc[4][4] = {};
    for (int nk = 0; nk < N_; nk += 16) {
        float4 k4 = *(const float4*)(kb + (size_t)(nk + lkk) * D_ + d0 + lmm);
        *(float4*)&Ks[lkk][lmm] = k4;
        float4 v4 = *(const float4*)(vb + (size_t)(nk + lkk) * D_ + e0 + lmm);
        *(float4*)&Vs[lkk][lmm] = v4;
        __syncthreads();
#pragma unroll
        for (int kk = 0; kk < 16; ++kk) {
            float4 a4 = *(const float4*)&Ks[kk][ty * 4];
            float4 w4 = *(const float4*)&Vs[kk][tx * 4];
            float a[4] = {a4.x, a4.y, a4.z, a4.w};
            float w[4] = {w4.x, w4.y, w4.z, w4.w};
#pragma unroll
            for (int i = 0; i < 4; ++i)
#pragma unroll
                for (int j = 0; j < 4; ++j)
                    acc[i][j] += a[i] * w[j];
        }
        __syncthreads();
    }
    float* out = kv + (size_t)b * D_ * D_;
#pragma unroll
    for (int i = 0; i < 4; ++i) {
        float4 vv; vv.x = acc[i][0]; vv.y = acc[i][1]; vv.z = acc[i][2]; vv.w = acc[i][3];
        *(float4*)(out + (size_t)(d0 + ty * 4 + i) * D_ + e0 + tx * 4) = vv;
    }
}

// ---------------------------------------------------------------------------
// kv2T[b,e,d] = sum_f proj_w[e,f] * kv[b,d,f]
// grid (3,3,BC)
// ---------------------------------------------------------------------------
__global__ __launch_bounds__(256) void kv2_k(
    const float* __restrict__ pw, const float* __restrict__ kv, float* __restrict__ kv2t)
{
    __shared__ float As[16][68];
    __shared__ float Ws[16][68];
    const int tid = threadIdx.x;
    const int tx = tid & 15, ty = tid >> 4;
    const int m0 = blockIdx.x * 64;   // e
    const int n0 = blockIdx.y * 64;   // d
    const int b = blockIdx.z;
    const float* kvb = kv + (size_t)b * D_ * D_;

    const int lm = tid >> 2;
    const int lk = (tid & 3) * 4;

    float acc[4][4] = {};
    for (int k0 = 0; k0 < D_; k0 += 16) {
        float4 av = *(const float4*)(pw + (size_t)(m0 + lm) * D_ + k0 + lk);
        As[lk + 0][lm] = av.x; As[lk + 1][lm] = av.y;
        As[lk + 2][lm] = av.z; As[lk + 3][lm] = av.w;
        float4 wv = *(const float4*)(kvb + (size_t)(n0 + lm) * D_ + k0 + lk);
        Ws[lk + 0][lm] = wv.x; Ws[lk + 1][lm] = wv.y;
        Ws[lk + 2][lm] = wv.z; Ws[lk + 3][lm] = wv.w;
        __syncthreads();
#pragma unroll
        for (int kk = 0; kk < 16; ++kk) {
            float4 a4 = *(const float4*)&As[kk][ty * 4];
            float4 w4 = *(const float4*)&Ws[kk][tx * 4];
            float a[4] = {a4.x, a4.y, a4.z, a4.w};
            float w[4] = {w4.x, w4.y, w4.z, w4.w};
#pragma unroll
            for (int i = 0; i < 4; ++i)
#pragma unroll
                for (int j = 0; j < 4; ++j)
                    acc[i][j] += a[i] * w[j];
        }
        __syncthreads();
    }
    float* out = kv2t + (size_t)b * D_ * D_;
#pragma unroll
    for (int i = 0; i < 4; ++i) {
        float4 vv; vv.x = acc[i][0]; vv.y = acc[i][1]; vv.z = acc[i][2]; vv.w = acc[i][3];
        *(float4*)(out + (size_t)(m0 + ty * 4 + i) * D_ + n0 + tx * 4) = vv;
    }
}

// ---------------------------------------------------------------------------
// invden[b] = 1 / (sum(q[b]) + 1e-6)
// ---------------------------------------------------------------------------
__global__ __launch_bounds__(256) void denom_k(
    const float* __restrict__ q, float* __restrict__ invden)
{
    const int b = blockIdx.x;
    const float* qb = q + (size_t)b * N_ * D_;
    float s = 0.f;
    for (int i = threadIdx.x; i < N_ * D_; i += 256) s += qb[i];
    __shared__ float red[256];
    red[threadIdx.x] = s;
    __syncthreads();
    for (int o = 128; o > 0; o >>= 1) {
        if (threadIdx.x < o) red[threadIdx.x] += red[threadIdx.x + o];
        __syncthreads();
    }
    if (threadIdx.x == 0) invden[b] = 1.f / (red[0] + 1e-6f);
}

// ---------------------------------------------------------------------------
// pooled = mean over n; out = pooled @ head_w.T + head_b
// ---------------------------------------------------------------------------
__global__ __launch_bounds__(192) void poolhead_k(
    const float* __restrict__ h, const float* __restrict__ hw,
    const float* __restrict__ hb, float* __restrict__ out)
{
    const int b = blockIdx.x, d = threadIdx.x;
    const float* hbp = h + (size_t)b * N_ * D_;
    float s = 0.f;
    for (int n = 0; n < N_; ++n) s += hbp[(size_t)n * D_ + d];
    __shared__ float pooled[D_];
    pooled[d] = s * (1.f / N_);
    __syncthreads();
    if (d < NC_) {
        float acc = hb[d];
        for (int e = 0; e < D_; ++e) acc += pooled[e] * hw[d * D_ + e];
        out[b * NC_ + d] = acc;
    }
}

// ---------------------------------------------------------------------------
extern "C" void kernel_launch(void* const* d_in, const int* in_sizes, int n_in,
                              void* d_out, int out_size, void* d_ws, size_t ws_size,
                              hipStream_t stream) {
    (void)in_sizes; (void)n_in; (void)out_size;

    const float* x      = (const float*)d_in[0];
    const float* conv_w = (const float*)d_in[1];
    const float* conv_b = (const float*)d_in[2];
    const float* pos    = (const float*)d_in[3];
    const float* qkv_w  = (const float*)d_in[4];
    const float* qkv_b  = (const float*)d_in[5];
    const float* proj_w = (const float*)d_in[6];
    const float* proj_b = (const float*)d_in[7];
    const float* ln1_g  = (const float*)d_in[8];
    const float* ln1_b  = (const float*)d_in[9];
    const float* mlp_w1 = (const float*)d_in[10];
    const float* mlp_b1 = (const float*)d_in[11];
    const float* mlp_w2 = (const float*)d_in[12];
    const float* mlp_b2 = (const float*)d_in[13];
    const float* ln2_g  = (const float*)d_in[14];
    const float* ln2_b  = (const float*)d_in[15];
    const float* head_w = (const float*)d_in[16];
    const float* head_b = (const float*)d_in[17];
    float* out = (float*)d_out;

    // ---- adaptive batch chunking so workspace fits ws_size ----
    // per-batch-element floats: h,q,k,v [N,D] each + kv,kv2t [D,D] + mean,rstd [N] + invd
    const size_t perB = (size_t)4 * N_ * D_ + (size_t)2 * D_ * D_ + 2 * N_ + 1;
    int BC = B_;
    while (BC > 1 && (size_t)BC * perB * sizeof(float) > ws_size) BC >>= 1;
    const int nchunks = B_ / BC;
    const size_t rows = (size_t)BC * N_;        // token rows per chunk

    float* ws   = (float*)d_ws;
    float* h    = ws;
    float* q    = h + (size_t)BC * N_ * D_;
    float* kb   = q + (size_t)BC * N_ * D_;
    float* vb   = kb + (size_t)BC * N_ * D_;
    float* kv   = vb + (size_t)BC * N_ * D_;
    float* kv2t = kv + (size_t)BC * D_ * D_;
    float* mean = kv2t + (size_t)BC * D_ * D_;
    float* rstd = mean + rows;
    float* invd = rstd + rows;
    float* mbuf = kb;  // m [rows,H] reuses k+v (dead after attn GEMM)

    for (int ch = 0; ch < nchunks; ++ch) {
        const int b0 = ch * BC;
        const float* xc = x + (size_t)b0 * C_ * N_;

        // 1. patch embed
        conv_k<<<dim3(N_ / 64, BC), 192, 0, stream>>>(xc, conv_w, conv_b, pos, h);
        // 2. LN1 stats
        lnstats_k<<<rows / 4, 256, 0, stream>>>(h, mean, rstd);
        // 3. qkv (fused LN1, relu on q,k)
        gemm_k<0, true><<<dim3(rows / 64, 9), 256, 0, stream>>>(
            h, qkv_w, D_, ln1_g, ln1_b, mean, rstd, qkv_b, nullptr, q, kb, vb, nullptr, 0);
        // 4. denominator
        denom_k<<<BC, 256, 0, stream>>>(q, invd);
        // 5. kv = k^T v (batched)
        kv_k<<<dim3(3, 3, BC), 256, 0, stream>>>(kb, vb, kv);
        // 6. kv2T = proj_w @ kv^T (batched, tiny)
        kv2_k<<<dim3(3, 3, BC), 256, 0, stream>>>(proj_w, kv, kv2t);
        // 7. h += (q @ kv2) * invden + proj_b
        gemm_k<3, false><<<dim3(rows / 64, 3), 256, 0, stream>>>(
            q, kv2t, D_, nullptr, nullptr, nullptr, nullptr, proj_b, invd,
            nullptr, nullptr, nullptr, h, 0);
        // 8. LN2 stats
        lnstats_k<<<rows / 4, 256, 0, stream>>>(h, mean, rstd);
        // 9. m = gelu(LN2(h) @ mlp_w1.T + b1)
        gemm_k<1, true><<<dim3(rows / 64, H_ / 64), 256, 0, stream>>>(
            h, mlp_w1, D_, ln2_g, ln2_b, mean, rstd, mlp_b1, nullptr,
            mbuf, nullptr, nullptr, nullptr, H_);
        // 10. h += m @ mlp_w2.T + b2
        gemm_k<2, false><<<dim3(rows / 64, D_ / 64), 256, 0, stream>>>(
            mbuf, mlp_w2, H_, nullptr, nullptr, nullptr, nullptr, mlp_b2, nullptr,
            nullptr, nullptr, nullptr, h, 0);
        // 11. pool + head
        poolhead_k<<<BC, 192, 0, stream>>>(h, head_w, head_b, out + (size_t)b0 * NC_);
    }
}

// Round 3
// 3137.839 us; speedup vs baseline: 1.5054x; 1.5054x over previous
//
#include <hip/hip_runtime.h>
#include <cmath>

// Problem constants
#define B_   128
#define C_   9
#define N_   2048
#define D_   192
#define H_   384
#define NC_  18

// ---------------------------------------------------------------------------
// conv1d(C->D, k=3, pad=1) + transpose to [BC,N,D] + pos_embed
// ---------------------------------------------------------------------------
__global__ __launch_bounds__(192) void conv_k(
    const float* __restrict__ x, const float* __restrict__ w,
    const float* __restrict__ cb, const float* __restrict__ pos,
    float* __restrict__ h)
{
    const int n0 = blockIdx.x * 64;
    const int b  = blockIdx.y;
    const int d  = threadIdx.x;

    __shared__ float xs[C_][66];
    for (int e = threadIdx.x; e < C_ * 66; e += 192) {
        int c = e / 66, i = e % 66;
        int n = n0 - 1 + i;
        xs[c][i] = (n >= 0 && n < N_) ? x[((size_t)b * C_ + c) * N_ + n] : 0.f;
    }

    float wr[C_][3];
#pragma unroll
    for (int c = 0; c < C_; ++c)
#pragma unroll
        for (int t = 0; t < 3; ++t)
            wr[c][t] = w[(d * C_ + c) * 3 + t];
    const float bias = cb[d];
    __syncthreads();

    for (int i = 0; i < 64; ++i) {
        int n = n0 + i;
        float acc = bias + pos[(size_t)n * D_ + d];
#pragma unroll
        for (int c = 0; c < C_; ++c)
#pragma unroll
            for (int t = 0; t < 3; ++t)
                acc += xs[c][i + t] * wr[c][t];
        h[((size_t)b * N_ + n) * D_ + d] = acc;
    }
}

// ---------------------------------------------------------------------------
// LayerNorm stats: one wave per row of 192
// ---------------------------------------------------------------------------
__global__ __launch_bounds__(256) void lnstats_k(
    const float* __restrict__ h, float* __restrict__ mean, float* __restrict__ rstd)
{
    const int wid = threadIdx.x >> 6, lane = threadIdx.x & 63;
    const int row = blockIdx.x * 4 + wid;
    const float* hr = h + (size_t)row * D_;
    float s = 0.f, q = 0.f;
#pragma unroll
    for (int i = 0; i < 3; ++i) { float v = hr[lane + i * 64]; s += v; q += v * v; }
#pragma unroll
    for (int o = 32; o > 0; o >>= 1) { s += __shfl_xor(s, o); q += __shfl_xor(q, o); }
    if (lane == 0) {
        float m = s * (1.f / D_);
        float var = q * (1.f / D_) - m * m;
        mean[row] = m;
        rstd[row] = rsqrtf(var + 1e-5f);
    }
}

// ---------------------------------------------------------------------------
// Generic tiled SGEMM: C[m,n] = sum_k A'[m,k] * W[n,k]   (W row-major [NW,K])
// EPI: 0 = qkv split (relu q,k) -> o0,o1,o2 ; q-sum atomicAdd into dsum[batch]
//      1 = gelu -> o0
//      2 = hacc += acc + bias
//      3 = hacc += acc/(dsum[b]+1e-6) + bias   (W batched per 2048 rows)
// ---------------------------------------------------------------------------
template <int EPI, bool LNA>
__global__ __launch_bounds__(256) void gemm_k(
    const float* __restrict__ A, const float* __restrict__ W, int K,
    const float* __restrict__ lng, const float* __restrict__ lnb,
    const float* __restrict__ mean, const float* __restrict__ rstd,
    const float* __restrict__ bias, float* __restrict__ dsum,
    float* __restrict__ o0, float* __restrict__ o1, float* __restrict__ o2,
    float* __restrict__ hacc, int ldo)
{
    __shared__ float As[16][68];
    __shared__ float Ws[16][68];

    const int tid = threadIdx.x;
    const int tx = tid & 15, ty = tid >> 4;
    const int m0 = blockIdx.x * 64;
    const int n0 = blockIdx.y * 64;
    const int batch = m0 >> 11;            // chunk-local batch index (2048 rows each)
    const float* Wp = W;
    if (EPI == 3) Wp += (size_t)batch * D_ * D_;

    const int lm = tid >> 2;               // 0..63
    const int lk = (tid & 3) * 4;          // 0,4,8,12
    const int arow = m0 + lm;
    float mu = 0.f, rs = 1.f;
    if (LNA) { mu = mean[arow]; rs = rstd[arow]; }

    float acc[4][4] = {};

    for (int k0 = 0; k0 < K; k0 += 16) {
        float4 av = *(const float4*)(A + (size_t)arow * K + k0 + lk);
        if (LNA) {
            float4 g4 = *(const float4*)(lng + k0 + lk);
            float4 b4 = *(const float4*)(lnb + k0 + lk);
            av.x = (av.x - mu) * rs * g4.x + b4.x;
            av.y = (av.y - mu) * rs * g4.y + b4.y;
            av.z = (av.z - mu) * rs * g4.z + b4.z;
            av.w = (av.w - mu) * rs * g4.w + b4.w;
        }
        As[lk + 0][lm] = av.x; As[lk + 1][lm] = av.y;
        As[lk + 2][lm] = av.z; As[lk + 3][lm] = av.w;

        float4 wv = *(const float4*)(Wp + (size_t)(n0 + lm) * K + k0 + lk);
        Ws[lk + 0][lm] = wv.x; Ws[lk + 1][lm] = wv.y;
        Ws[lk + 2][lm] = wv.z; Ws[lk + 3][lm] = wv.w;
        __syncthreads();

#pragma unroll
        for (int kk = 0; kk < 16; ++kk) {
            float4 a4 = *(const float4*)&As[kk][ty * 4];
            float4 w4 = *(const float4*)&Ws[kk][tx * 4];
            float a[4] = {a4.x, a4.y, a4.z, a4.w};
            float w[4] = {w4.x, w4.y, w4.z, w4.w};
#pragma unroll
            for (int i = 0; i < 4; ++i)
#pragma unroll
                for (int j = 0; j < 4; ++j)
                    acc[i][j] += a[i] * w[j];
        }
        __syncthreads();
    }

    const int row_base = m0 + ty * 4;
    const int col_base = n0 + tx * 4;

    if (EPI == 0) {
        const int region = blockIdx.y / 3;               // 0:q 1:k 2:v
        float* dst = (region == 0) ? o0 : (region == 1 ? o1 : o2);
        const int cb0 = col_base - region * D_;
        float qsum = 0.f;
#pragma unroll
        for (int i = 0; i < 4; ++i) {
            int row = row_base + i;
            float4 vv;
            float t[4];
#pragma unroll
            for (int j = 0; j < 4; ++j) {
                float v = acc[i][j] + bias[col_base + j];
                if (region < 2) v = fmaxf(v, 0.f);
                t[j] = v;
                qsum += v;
            }
            vv.x = t[0]; vv.y = t[1]; vv.z = t[2]; vv.w = t[3];
            *(float4*)(dst + (size_t)row * D_ + cb0) = vv;
        }
        if (region == 0) {   // block-uniform branch
            __shared__ float red[256];
            red[tid] = qsum;
            __syncthreads();
            for (int o = 128; o > 0; o >>= 1) {
                if (tid < o) red[tid] += red[tid + o];
                __syncthreads();
            }
            if (tid == 0) atomicAdd(dsum + batch, red[0]);
        }
    } else if (EPI == 1) {
#pragma unroll
        for (int i = 0; i < 4; ++i) {
            int row = row_base + i;
            float4 vv;
            float t[4];
#pragma unroll
            for (int j = 0; j < 4; ++j) {
                float v = acc[i][j] + bias[col_base + j];
                t[j] = 0.5f * v * (1.f + erff(v * 0.70710678118654752f));
            }
            vv.x = t[0]; vv.y = t[1]; vv.z = t[2]; vv.w = t[3];
            *(float4*)(o0 + (size_t)row * ldo + col_base) = vv;
        }
    } else if (EPI == 2) {
#pragma unroll
        for (int i = 0; i < 4; ++i) {
            int row = row_base + i;
            float4 hv = *(float4*)(hacc + (size_t)row * D_ + col_base);
            hv.x += acc[i][0] + bias[col_base + 0];
            hv.y += acc[i][1] + bias[col_base + 1];
            hv.z += acc[i][2] + bias[col_base + 2];
            hv.w += acc[i][3] + bias[col_base + 3];
            *(float4*)(hacc + (size_t)row * D_ + col_base) = hv;
        }
    } else if (EPI == 3) {
        const float s = 1.f / (dsum[batch] + 1e-6f);
#pragma unroll
        for (int i = 0; i < 4; ++i) {
            int row = row_base + i;
            float4 hv = *(float4*)(hacc + (size_t)row * D_ + col_base);
            hv.x += acc[i][0] * s + bias[col_base + 0];
            hv.y += acc[i][1] * s + bias[col_base + 1];
            hv.z += acc[i][2] * s + bias[col_base + 2];
            hv.w += acc[i][3] * s + bias[col_base + 3];
            *(float4*)(hacc + (size_t)row * D_ + col_base) = hv;
        }
    }
}

// ---------------------------------------------------------------------------
// kv[b,d,e] = sum_n k[b,n,d] * v[b,n,e]
// ---------------------------------------------------------------------------
__global__ __launch_bounds__(256) void kv_k(
    const float* __restrict__ kq, const float* __restrict__ vq, float* __restrict__ kv)
{
    __shared__ float Ks[16][68];
    __shared__ float Vs[16][68];
    const int tid = threadIdx.x;
    const int tx = tid & 15, ty = tid >> 4;
    const int d0 = blockIdx.x * 64, e0 = blockIdx.y * 64, b = blockIdx.z;
    const float* kb = kq + (size_t)b * N_ * D_;
    const float* vb = vq + (size_t)b * N_ * D_;

    const int lkk = tid >> 4;
    const int lmm = (tid & 15) * 4;

    float acc[4][4] = {};
    for (int nk = 0; nk < N_; nk += 16) {
        float4 k4 = *(const float4*)(kb + (size_t)(nk + lkk) * D_ + d0 + lmm);
        *(float4*)&Ks[lkk][lmm] = k4;
        float4 v4 = *(const float4*)(vb + (size_t)(nk + lkk) * D_ + e0 + lmm);
        *(float4*)&Vs[lkk][lmm] = v4;
        __syncthreads();
#pragma unroll
        for (int kk = 0; kk < 16; ++kk) {
            float4 a4 = *(const float4*)&Ks[kk][ty * 4];
            float4 w4 = *(const float4*)&Vs[kk][tx * 4];
            float a[4] = {a4.x, a4.y, a4.z, a4.w};
            float w[4] = {w4.x, w4.y, w4.z, w4.w};
#pragma unroll
            for (int i = 0; i < 4; ++i)
#pragma unroll
                for (int j = 0; j < 4; ++j)
                    acc[i][j] += a[i] * w[j];
        }
        __syncthreads();
    }
    float* out = kv + (size_t)b * D_ * D_;
#pragma unroll
    for (int i = 0; i < 4; ++i) {
        float4 vv; vv.x = acc[i][0]; vv.y = acc[i][1]; vv.z = acc[i][2]; vv.w = acc[i][3];
        *(float4*)(out + (size_t)(d0 + ty * 4 + i) * D_ + e0 + tx * 4) = vv;
    }
}

// ---------------------------------------------------------------------------
// kv2T[b,e,d] = sum_f proj_w[e,f] * kv[b,d,f]
// ---------------------------------------------------------------------------
__global__ __launch_bounds__(256) void kv2_k(
    const float* __restrict__ pw, const float* __restrict__ kv, float* __restrict__ kv2t)
{
    __shared__ float As[16][68];
    __shared__ float Ws[16][68];
    const int tid = threadIdx.x;
    const int tx = tid & 15, ty = tid >> 4;
    const int m0 = blockIdx.x * 64;
    const int n0 = blockIdx.y * 64;
    const int b = blockIdx.z;
    const float* kvb = kv + (size_t)b * D_ * D_;

    const int lm = tid >> 2;
    const int lk = (tid & 3) * 4;

    float acc[4][4] = {};
    for (int k0 = 0; k0 < D_; k0 += 16) {
        float4 av = *(const float4*)(pw + (size_t)(m0 + lm) * D_ + k0 + lk);
        As[lk + 0][lm] = av.x; As[lk + 1][lm] = av.y;
        As[lk + 2][lm] = av.z; As[lk + 3][lm] = av.w;
        float4 wv = *(const float4*)(kvb + (size_t)(n0 + lm) * D_ + k0 + lk);
        Ws[lk + 0][lm] = wv.x; Ws[lk + 1][lm] = wv.y;
        Ws[lk + 2][lm] = wv.z; Ws[lk + 3][lm] = wv.w;
        __syncthreads();
#pragma unroll
        for (int kk = 0; kk < 16; ++kk) {
            float4 a4 = *(const float4*)&As[kk][ty * 4];
            float4 w4 = *(const float4*)&Ws[kk][tx * 4];
            float a[4] = {a4.x, a4.y, a4.z, a4.w};
            float w[4] = {w4.x, w4.y, w4.z, w4.w};
#pragma unroll
            for (int i = 0; i < 4; ++i)
#pragma unroll
                for (int j = 0; j < 4; ++j)
                    acc[i][j] += a[i] * w[j];
        }
        __syncthreads();
    }
    float* out = kv2t + (size_t)b * D_ * D_;
#pragma unroll
    for (int i = 0; i < 4; ++i) {
        float4 vv; vv.x = acc[i][0]; vv.y = acc[i][1]; vv.z = acc[i][2]; vv.w = acc[i][3];
        *(float4*)(out + (size_t)(m0 + ty * 4 + i) * D_ + n0 + tx * 4) = vv;
    }
}

// ---------------------------------------------------------------------------
// pool partial: grid (N/64, BC), block 192. atomicAdd 64-row sums into pooled[b][d].
// ---------------------------------------------------------------------------
__global__ __launch_bounds__(192) void pool_k(
    const float* __restrict__ h, float* __restrict__ pooled)
{
    const int n0 = blockIdx.x * 64;
    const int b  = blockIdx.y;
    const int d  = threadIdx.x;
    const float* hb = h + ((size_t)b * N_ + n0) * D_;
    float s = 0.f;
#pragma unroll 8
    for (int i = 0; i < 64; ++i) s += hb[(size_t)i * D_ + d];
    atomicAdd(pooled + (size_t)b * D_ + d, s);
}

// ---------------------------------------------------------------------------
// head: out[b,:] = (pooled[b,:]/N) @ head_w.T + head_b
// ---------------------------------------------------------------------------
__global__ __launch_bounds__(192) void head_k(
    const float* __restrict__ pooled, const float* __restrict__ hw,
    const float* __restrict__ hb, float* __restrict__ out)
{
    const int b = blockIdx.x, d = threadIdx.x;
    __shared__ float p[D_];
    p[d] = pooled[(size_t)b * D_ + d] * (1.f / N_);
    __syncthreads();
    if (d < NC_) {
        float acc = hb[d];
        for (int e = 0; e < D_; ++e) acc += p[e] * hw[d * D_ + e];
        out[b * NC_ + d] = acc;
    }
}

// ---------------------------------------------------------------------------
extern "C" void kernel_launch(void* const* d_in, const int* in_sizes, int n_in,
                              void* d_out, int out_size, void* d_ws, size_t ws_size,
                              hipStream_t stream) {
    (void)in_sizes; (void)n_in; (void)out_size;

    const float* x      = (const float*)d_in[0];
    const float* conv_w = (const float*)d_in[1];
    const float* conv_b = (const float*)d_in[2];
    const float* pos    = (const float*)d_in[3];
    const float* qkv_w  = (const float*)d_in[4];
    const float* qkv_b  = (const float*)d_in[5];
    const float* proj_w = (const float*)d_in[6];
    const float* proj_b = (const float*)d_in[7];
    const float* ln1_g  = (const float*)d_in[8];
    const float* ln1_b  = (const float*)d_in[9];
    const float* mlp_w1 = (const float*)d_in[10];
    const float* mlp_b1 = (const float*)d_in[11];
    const float* mlp_w2 = (const float*)d_in[12];
    const float* mlp_b2 = (const float*)d_in[13];
    const float* ln2_g  = (const float*)d_in[14];
    const float* ln2_b  = (const float*)d_in[15];
    const float* head_w = (const float*)d_in[16];
    const float* head_b = (const float*)d_in[17];
    float* out = (float*)d_out;

    // ---- adaptive batch chunking so workspace fits ws_size ----
    const size_t perB = (size_t)4 * N_ * D_ + (size_t)2 * D_ * D_ + 2 * N_ + D_ + 2;
    int BC = B_;
    while (BC > 1 && (size_t)BC * perB * sizeof(float) > ws_size) BC >>= 1;
    const int nchunks = B_ / BC;
    const size_t rows = (size_t)BC * N_;

    float* ws     = (float*)d_ws;
    float* h      = ws;
    float* q      = h + (size_t)BC * N_ * D_;
    float* kb     = q + (size_t)BC * N_ * D_;
    float* vb     = kb + (size_t)BC * N_ * D_;
    float* kv     = vb + (size_t)BC * N_ * D_;
    float* kv2t   = kv + (size_t)BC * D_ * D_;
    float* mean   = kv2t + (size_t)BC * D_ * D_;
    float* rstd   = mean + rows;
    float* dsum   = rstd + rows;
    float* pooled = dsum + BC;
    float* mbuf   = kb;  // m [rows,H] reuses k+v

    for (int ch = 0; ch < nchunks; ++ch) {
        const int b0 = ch * BC;
        const float* xc = x + (size_t)b0 * C_ * N_;

        hipMemsetAsync(dsum, 0, (size_t)BC * sizeof(float), stream);
        hipMemsetAsync(pooled, 0, (size_t)BC * D_ * sizeof(float), stream);

        // 1. patch embed
        conv_k<<<dim3(N_ / 64, BC), 192, 0, stream>>>(xc, conv_w, conv_b, pos, h);
        // 2. LN1 stats
        lnstats_k<<<rows / 4, 256, 0, stream>>>(h, mean, rstd);
        // 3. qkv (fused LN1, relu on q,k, q-sum -> dsum)
        gemm_k<0, true><<<dim3(rows / 64, 9), 256, 0, stream>>>(
            h, qkv_w, D_, ln1_g, ln1_b, mean, rstd, qkv_b, dsum, q, kb, vb, nullptr, 0);
        // 4. kv = k^T v (batched)
        kv_k<<<dim3(3, 3, BC), 256, 0, stream>>>(kb, vb, kv);
        // 5. kv2T = proj_w @ kv^T (batched, tiny)
        kv2_k<<<dim3(3, 3, BC), 256, 0, stream>>>(proj_w, kv, kv2t);
        // 6. h += (q @ kv2) / (dsum+1e-6) + proj_b
        gemm_k<3, false><<<dim3(rows / 64, 3), 256, 0, stream>>>(
            q, kv2t, D_, nullptr, nullptr, nullptr, nullptr, proj_b, dsum,
            nullptr, nullptr, nullptr, h, 0);
        // 7. LN2 stats
        lnstats_k<<<rows / 4, 256, 0, stream>>>(h, mean, rstd);
        // 8. m = gelu(LN2(h) @ mlp_w1.T + b1)
        gemm_k<1, true><<<dim3(rows / 64, H_ / 64), 256, 0, stream>>>(
            h, mlp_w1, D_, ln2_g, ln2_b, mean, rstd, mlp_b1, nullptr,
            mbuf, nullptr, nullptr, nullptr, H_);
        // 9. h += m @ mlp_w2.T + b2
        gemm_k<2, false><<<dim3(rows / 64, D_ / 64), 256, 0, stream>>>(
            mbuf, mlp_w2, H_, nullptr, nullptr, nullptr, nullptr, mlp_b2, nullptr,
            nullptr, nullptr, nullptr, h, 0);
        // 10. pool + head
        pool_k<<<dim3(N_ / 64, BC), 192, 0, stream>>>(h, pooled);
        head_k<<<BC, 192, 0, stream>>>(pooled, head_w, head_b, out + (size_t)b0 * NC_);
    }
}

// Round 4
// 2099.466 us; speedup vs baseline: 2.2499x; 1.4946x over previous
//
#include <hip/hip_runtime.h>
#include <cmath>

#define B_   128
#define C_   9
#define N_   2048
#define D_   192
#define H_   384
#define NC_  18

typedef unsigned short ushort_t;
typedef __attribute__((ext_vector_type(8))) __bf16 bf16x8;
typedef __attribute__((ext_vector_type(8))) short short8;
typedef __attribute__((ext_vector_type(16))) float f32x16;

__device__ __forceinline__ ushort_t f2bf(float x) {
    unsigned u = __float_as_uint(x);
    return (ushort_t)((u + 0x7fffu + ((u >> 16) & 1u)) >> 16);
}
__device__ __forceinline__ float bf2f(ushort_t h) {
    return __uint_as_float(((unsigned)h) << 16);
}
__device__ __forceinline__ bf16x8 ldfrag(const ushort_t* p) {
    short8 s = *(const short8*)p;
    return __builtin_bit_cast(bf16x8, s);
}

// ---------------------------------------------------------------------------
// conv1d(C->D,k=3,pad=1) + transpose + pos_embed -> h [BC*N, D] f32
// ---------------------------------------------------------------------------
__global__ __launch_bounds__(192) void conv_k(
    const float* __restrict__ x, const float* __restrict__ w,
    const float* __restrict__ cb, const float* __restrict__ pos,
    float* __restrict__ h)
{
    const int n0 = blockIdx.x * 64;
    const int b  = blockIdx.y;
    const int d  = threadIdx.x;

    __shared__ float xs[C_][66];
    for (int e = threadIdx.x; e < C_ * 66; e += 192) {
        int c = e / 66, i = e % 66;
        int n = n0 - 1 + i;
        xs[c][i] = (n >= 0 && n < N_) ? x[((size_t)b * C_ + c) * N_ + n] : 0.f;
    }
    float wr[C_][3];
#pragma unroll
    for (int c = 0; c < C_; ++c)
#pragma unroll
        for (int t = 0; t < 3; ++t) wr[c][t] = w[(d * C_ + c) * 3 + t];
    const float bias = cb[d];
    __syncthreads();
    for (int i = 0; i < 64; ++i) {
        int n = n0 + i;
        float acc = bias + pos[(size_t)n * D_ + d];
#pragma unroll
        for (int c = 0; c < C_; ++c)
#pragma unroll
            for (int t = 0; t < 3; ++t) acc += xs[c][i + t] * wr[c][t];
        h[((size_t)b * N_ + n) * D_ + d] = acc;
    }
}

// ---------------------------------------------------------------------------
// LN stats, one wave per row of 192
// ---------------------------------------------------------------------------
__global__ __launch_bounds__(256) void lnstats_k(
    const float* __restrict__ h, float* __restrict__ mean, float* __restrict__ rstd)
{
    const int wid = threadIdx.x >> 6, lane = threadIdx.x & 63;
    const int row = blockIdx.x * 4 + wid;
    const float* hr = h + (size_t)row * D_;
    float s = 0.f, q = 0.f;
#pragma unroll
    for (int i = 0; i < 3; ++i) { float v = hr[lane + i * 64]; s += v; q += v * v; }
#pragma unroll
    for (int o = 32; o > 0; o >>= 1) { s += __shfl_xor(s, o); q += __shfl_xor(q, o); }
    if (lane == 0) {
        float m = s * (1.f / D_);
        float var = q * (1.f / D_) - m * m;
        mean[row] = m;
        rstd[row] = rsqrtf(var + 1e-5f);
    }
}

// ---------------------------------------------------------------------------
// split f32 -> (hi,lo) bf16 planes
// ---------------------------------------------------------------------------
__global__ __launch_bounds__(256) void splitw_k(
    const float* __restrict__ w, ushort_t* __restrict__ hi, ushort_t* __restrict__ lo, int n)
{
    int i = blockIdx.x * 256 + threadIdx.x;
    if (i < n) {
        float v = w[i];
        ushort_t hb = f2bf(v);
        hi[i] = hb;
        lo[i] = f2bf(v - bf2f(hb));
    }
}

// ---------------------------------------------------------------------------
// transpose k,v [BC*N, D] f32 -> kT,vT [BC*D, N] split bf16 planes
// grid (N/32, D/32, BC*2), block 256
// ---------------------------------------------------------------------------
__global__ __launch_bounds__(256) void transpose_k(
    const float* __restrict__ kb, const float* __restrict__ vb,
    ushort_t* __restrict__ kTh, ushort_t* __restrict__ kTl,
    ushort_t* __restrict__ vTh, ushort_t* __restrict__ vTl)
{
    const int n0 = blockIdx.x * 32, d0 = blockIdx.y * 32;
    const int b = blockIdx.z >> 1, which = blockIdx.z & 1;
    const float* src = which ? vb : kb;
    ushort_t* dh = which ? vTh : kTh;
    ushort_t* dl = which ? vTl : kTl;

    __shared__ float t[32][33];
    {
        int r = threadIdx.x >> 3, cq = (threadIdx.x & 7) * 4;
        float4 v4 = *(const float4*)(src + ((size_t)b * N_ + n0 + r) * D_ + d0 + cq);
        t[r][cq + 0] = v4.x; t[r][cq + 1] = v4.y; t[r][cq + 2] = v4.z; t[r][cq + 3] = v4.w;
    }
    __syncthreads();
    {
        int d = threadIdx.x >> 3, rq = (threadIdx.x & 7) * 4;
        ushort_t hb[4], lb[4];
#pragma unroll
        for (int i = 0; i < 4; ++i) {
            float v = t[rq + i][d];
            hb[i] = f2bf(v);
            lb[i] = f2bf(v - bf2f(hb[i]));
        }
        size_t base = ((size_t)b * D_ + d0 + d) * N_ + n0 + rq;
        *(uint2*)&dh[base] = make_uint2((unsigned)hb[0] | ((unsigned)hb[1] << 16),
                                        (unsigned)hb[2] | ((unsigned)hb[3] << 16));
        *(uint2*)&dl[base] = make_uint2((unsigned)lb[0] | ((unsigned)lb[1] << 16),
                                        (unsigned)lb[2] | ((unsigned)lb[3] << 16));
    }
}

// ---------------------------------------------------------------------------
// MFMA GEMM: C[m,n] = sum_k A[m,k]*W[n,k], split-bf16 (hi/lo planes).
// BM=64, BN=192, BK=32, 256 threads = 4 waves (2x2), 32x32x16 mfma.
// EPI 0: qkv (region=by: 0 q->split+qsum, 1 k->f32 relu, 2 v->f32)
// EPI 1: gelu -> split (o_hi/o_lo, ld=H)
// EPI 2: hacc += acc + bias
// EPI 3: hacc += acc/(dsum[b]+1e-6) + bias, W batched per 2048 rows
// EPI 4: atomicAdd into o0 (kv), A rows = BC*192, W batched per 192 rows, K-split via grid.z
// ---------------------------------------------------------------------------
template <int EPI, bool LNA, bool APRE>
__global__ __launch_bounds__(256) void mgemm(
    const float* __restrict__ Af, const ushort_t* __restrict__ Ah, const ushort_t* __restrict__ Al,
    int K,
    const ushort_t* __restrict__ Wh, const ushort_t* __restrict__ Wl,
    const float* __restrict__ lng, const float* __restrict__ lnb,
    const float* __restrict__ mean, const float* __restrict__ rstd,
    const float* __restrict__ bias, float* __restrict__ dsum,
    ushort_t* __restrict__ oh, ushort_t* __restrict__ ol,
    float* __restrict__ o0, float* __restrict__ o1, float* __restrict__ hacc)
{
    __shared__ ushort_t smem[16384];
    ushort_t* sAh = smem;            // [4][64][8]
    ushort_t* sAl = smem + 2048;
    ushort_t* sWh = smem + 4096;     // [4][192][8]
    ushort_t* sWl = smem + 10240;

    const int tid = threadIdx.x;
    const int bx = blockIdx.x, by = blockIdx.y;
    const int m0 = bx * 64;
    const int lane = tid & 63;
    const int l5 = lane >> 5;
    const int wid = tid >> 6;
    const int wr = wid >> 1, wc = wid & 1;

    // W base offset (per EPI batching)
    size_t wbase = 0;
    if (EPI == 0 || EPI == 1) wbase = (size_t)by * 192 * K;
    else if (EPI == 3) wbase = (size_t)(bx >> 5) * D_ * D_;
    else if (EPI == 4) wbase = (size_t)(bx / 3) * D_ * (size_t)K;
    const ushort_t* Whp = Wh + wbase;
    const ushort_t* Wlp = Wl + wbase;

    // k range (K-split for EPI 4)
    int kbeg = 0, kend = K;
    if (EPI == 4) {
        int seg = K / gridDim.z;
        kbeg = blockIdx.z * seg;
        kend = kbeg + seg;
    }

    // hoisted LN params (LN staging path: 2 rows per thread)
    float mu0 = 0.f, rs0 = 1.f, mu1 = 0.f, rs1 = 1.f;
    if (!APRE && LNA) {
        int r0 = m0 + (tid >> 3);
        mu0 = mean[r0]; rs0 = rstd[r0];
        mu1 = mean[r0 + 32]; rs1 = rstd[r0 + 32];
    }

    // fragment LDS offsets
    const int aoff = (wr * 32 + (lane & 31)) * 8 + l5 * 512;
    const int woff = (wc * 96 + (lane & 31)) * 8 + l5 * 1536;

    f32x16 acc[3] = {};

    for (int k0 = kbeg; k0 < kend; k0 += 32) {
        // ---- stage A ----
        if (APRE) {
            int row = tid >> 2, koct = tid & 3;
            size_t g = (size_t)(m0 + row) * K + k0 + koct * 8;
            *(uint4*)&sAh[(koct * 64 + row) * 8] = *(const uint4*)(Ah + g);
            *(uint4*)&sAl[(koct * 64 + row) * 8] = *(const uint4*)(Al + g);
        } else {
            const int kq = tid & 7;
            float4 g4, b4;
            if (LNA) {
                g4 = *(const float4*)(lng + k0 + kq * 4);
                b4 = *(const float4*)(lnb + k0 + kq * 4);
            }
#pragma unroll
            for (int p = 0; p < 2; ++p) {
                int row = (tid >> 3) + p * 32;
                float4 av = *(const float4*)(Af + (size_t)(m0 + row) * K + k0 + kq * 4);
                if (LNA) {
                    float mu = p ? mu1 : mu0, rs = p ? rs1 : rs0;
                    av.x = (av.x - mu) * rs * g4.x + b4.x;
                    av.y = (av.y - mu) * rs * g4.y + b4.y;
                    av.z = (av.z - mu) * rs * g4.z + b4.z;
                    av.w = (av.w - mu) * rs * g4.w + b4.w;
                }
                float vv[4] = {av.x, av.y, av.z, av.w};
                ushort_t hb[4], lb[4];
#pragma unroll
                for (int j = 0; j < 4; ++j) {
                    hb[j] = f2bf(vv[j]);
                    lb[j] = f2bf(vv[j] - bf2f(hb[j]));
                }
                int koct = kq >> 1, j0 = (kq & 1) * 4;
                int da = (koct * 64 + row) * 8 + j0;
                *(uint2*)&sAh[da] = make_uint2((unsigned)hb[0] | ((unsigned)hb[1] << 16),
                                               (unsigned)hb[2] | ((unsigned)hb[3] << 16));
                *(uint2*)&sAl[da] = make_uint2((unsigned)lb[0] | ((unsigned)lb[1] << 16),
                                               (unsigned)lb[2] | ((unsigned)lb[3] << 16));
            }
        }
        // ---- stage W (pre-split bf16) ----
#pragma unroll
        for (int s = 0; s < 3; ++s) {
            int slot = tid + s * 256;
            int n = slot >> 2, koct = slot & 3;
            size_t g = (size_t)n * K + k0 + koct * 8;
            *(uint4*)&sWh[(koct * 192 + n) * 8] = *(const uint4*)(Whp + g);
            *(uint4*)&sWl[(koct * 192 + n) * 8] = *(const uint4*)(Wlp + g);
        }
        __syncthreads();

        // ---- compute ----
#pragma unroll
        for (int kh = 0; kh < 2; ++kh) {
            bf16x8 ahf = ldfrag(&sAh[aoff + kh * 1024]);
            bf16x8 alf = ldfrag(&sAl[aoff + kh * 1024]);
#pragma unroll
            for (int tn = 0; tn < 3; ++tn) {
                bf16x8 whf = ldfrag(&sWh[woff + kh * 3072 + tn * 256]);
                bf16x8 wlf = ldfrag(&sWl[woff + kh * 3072 + tn * 256]);
                acc[tn] = __builtin_amdgcn_mfma_f32_32x32x16_bf16(ahf, whf, acc[tn], 0, 0, 0);
                acc[tn] = __builtin_amdgcn_mfma_f32_32x32x16_bf16(ahf, wlf, acc[tn], 0, 0, 0);
                acc[tn] = __builtin_amdgcn_mfma_f32_32x32x16_bf16(alf, whf, acc[tn], 0, 0, 0);
            }
        }
        __syncthreads();
    }

    // ---- epilogue ----
    const int rb = m0 + wr * 32 + 4 * l5;
    const int cb = wc * 96 + (lane & 31);

    if (EPI == 0) {
        float qsum = 0.f;
#pragma unroll
        for (int tn = 0; tn < 3; ++tn) {
            const int col = cb + tn * 32;
            const float bv = bias[by * 192 + col];
#pragma unroll
            for (int r = 0; r < 16; ++r) {
                int row = rb + (r & 3) + 8 * (r >> 2);
                float v = acc[tn][r] + bv;
                if (by < 2) v = fmaxf(v, 0.f);
                if (by == 0) {
                    qsum += v;
                    ushort_t hb = f2bf(v);
                    oh[(size_t)row * D_ + col] = hb;
                    ol[(size_t)row * D_ + col] = f2bf(v - bf2f(hb));
                } else if (by == 1) {
                    o0[(size_t)row * D_ + col] = v;
                } else {
                    o1[(size_t)row * D_ + col] = v;
                }
            }
        }
        if (by == 0) {
            __syncthreads();
            float* red = (float*)smem;
            red[tid] = qsum;
            __syncthreads();
            for (int o = 128; o > 0; o >>= 1) {
                if (tid < o) red[tid] += red[tid + o];
                __syncthreads();
            }
            if (tid == 0) atomicAdd(&dsum[bx >> 5], red[0]);
        }
    } else if (EPI == 1) {
#pragma unroll
        for (int tn = 0; tn < 3; ++tn) {
            const int col = cb + tn * 32;
            const int colg = by * 192 + col;
            const float bv = bias[colg];
#pragma unroll
            for (int r = 0; r < 16; ++r) {
                int row = rb + (r & 3) + 8 * (r >> 2);
                float v = acc[tn][r] + bv;
                float g = 0.5f * v * (1.f + erff(v * 0.70710678118654752f));
                ushort_t hb = f2bf(g);
                oh[(size_t)row * H_ + colg] = hb;
                ol[(size_t)row * H_ + colg] = f2bf(g - bf2f(hb));
            }
        }
    } else if (EPI == 2) {
#pragma unroll
        for (int tn = 0; tn < 3; ++tn) {
            const int col = cb + tn * 32;
            const float bv = bias[col];
#pragma unroll
            for (int r = 0; r < 16; ++r) {
                int row = rb + (r & 3) + 8 * (r >> 2);
                hacc[(size_t)row * D_ + col] += acc[tn][r] + bv;
            }
        }
    } else if (EPI == 3) {
        const float s = 1.f / (dsum[bx >> 5] + 1e-6f);
#pragma unroll
        for (int tn = 0; tn < 3; ++tn) {
            const int col = cb + tn * 32;
            const float bv = bias[col];
#pragma unroll
            for (int r = 0; r < 16; ++r) {
                int row = rb + (r & 3) + 8 * (r >> 2);
                hacc[(size_t)row * D_ + col] += acc[tn][r] * s + bv;
            }
        }
    } else if (EPI == 4) {
#pragma unroll
        for (int tn = 0; tn < 3; ++tn) {
            const int col = cb + tn * 32;
#pragma unroll
            for (int r = 0; r < 16; ++r) {
                int row = rb + (r & 3) + 8 * (r >> 2);
                atomicAdd(&o0[(size_t)row * D_ + col], acc[tn][r]);
            }
        }
    }
}

// ---------------------------------------------------------------------------
// kv2T[b,e,d] = sum_f proj_w[e,f]*kv[b,d,f]  -> split bf16 output
// ---------------------------------------------------------------------------
__global__ __launch_bounds__(256) void kv2_k(
    const float* __restrict__ pw, const float* __restrict__ kv,
    ushort_t* __restrict__ oh, ushort_t* __restrict__ ol)
{
    __shared__ float As[16][68];
    __shared__ float Ws[16][68];
    const int tid = threadIdx.x;
    const int tx = tid & 15, ty = tid >> 4;
    const int m0 = blockIdx.x * 64;   // e
    const int n0 = blockIdx.y * 64;   // d
    const int b = blockIdx.z;
    const float* kvb = kv + (size_t)b * D_ * D_;
    const int lm = tid >> 2;
    const int lk = (tid & 3) * 4;

    float acc[4][4] = {};
    for (int k0 = 0; k0 < D_; k0 += 16) {
        float4 av = *(const float4*)(pw + (size_t)(m0 + lm) * D_ + k0 + lk);
        As[lk + 0][lm] = av.x; As[lk + 1][lm] = av.y;
        As[lk + 2][lm] = av.z; As[lk + 3][lm] = av.w;
        float4 wv = *(const float4*)(kvb + (size_t)(n0 + lm) * D_ + k0 + lk);
        Ws[lk + 0][lm] = wv.x; Ws[lk + 1][lm] = wv.y;
        Ws[lk + 2][lm] = wv.z; Ws[lk + 3][lm] = wv.w;
        __syncthreads();
#pragma unroll
        for (int kk = 0; kk < 16; ++kk) {
            float4 a4 = *(const float4*)&As[kk][ty * 4];
            float4 w4 = *(const float4*)&Ws[kk][tx * 4];
            float a[4] = {a4.x, a4.y, a4.z, a4.w};
            float w[4] = {w4.x, w4.y, w4.z, w4.w};
#pragma unroll
            for (int i = 0; i < 4; ++i)
#pragma unroll
                for (int j = 0; j < 4; ++j) acc[i][j] += a[i] * w[j];
        }
        __syncthreads();
    }
#pragma unroll
    for (int i = 0; i < 4; ++i) {
        ushort_t hb[4], lb[4];
#pragma unroll
        for (int j = 0; j < 4; ++j) {
            float v = acc[i][j];
            hb[j] = f2bf(v);
            lb[j] = f2bf(v - bf2f(hb[j]));
        }
        size_t base = (size_t)b * D_ * D_ + (size_t)(m0 + ty * 4 + i) * D_ + n0 + tx * 4;
        *(uint2*)&oh[base] = make_uint2((unsigned)hb[0] | ((unsigned)hb[1] << 16),
                                        (unsigned)hb[2] | ((unsigned)hb[3] << 16));
        *(uint2*)&ol[base] = make_uint2((unsigned)lb[0] | ((unsigned)lb[1] << 16),
                                        (unsigned)lb[2] | ((unsigned)lb[3] << 16));
    }
}

// ---------------------------------------------------------------------------
__global__ __launch_bounds__(192) void pool_k(
    const float* __restrict__ h, float* __restrict__ pooled)
{
    const int n0 = blockIdx.x * 64;
    const int b  = blockIdx.y;
    const int d  = threadIdx.x;
    const float* hb = h + ((size_t)b * N_ + n0) * D_;
    float s = 0.f;
#pragma unroll 8
    for (int i = 0; i < 64; ++i) s += hb[(size_t)i * D_ + d];
    atomicAdd(pooled + (size_t)b * D_ + d, s);
}

__global__ __launch_bounds__(192) void head_k(
    const float* __restrict__ pooled, const float* __restrict__ hw,
    const float* __restrict__ hb, float* __restrict__ out)
{
    const int b = blockIdx.x, d = threadIdx.x;
    __shared__ float p[D_];
    p[d] = pooled[(size_t)b * D_ + d] * (1.f / N_);
    __syncthreads();
    if (d < NC_) {
        float acc = hb[d];
        for (int e = 0; e < D_; ++e) acc += p[e] * hw[d * D_ + e];
        out[b * NC_ + d] = acc;
    }
}

// ---------------------------------------------------------------------------
extern "C" void kernel_launch(void* const* d_in, const int* in_sizes, int n_in,
                              void* d_out, int out_size, void* d_ws, size_t ws_size,
                              hipStream_t stream) {
    (void)in_sizes; (void)n_in; (void)out_size;

    const float* x      = (const float*)d_in[0];
    const float* conv_w = (const float*)d_in[1];
    const float* conv_b = (const float*)d_in[2];
    const float* pos    = (const float*)d_in[3];
    const float* qkv_w  = (const float*)d_in[4];
    const float* qkv_b  = (const float*)d_in[5];
    const float* proj_w = (const float*)d_in[6];
    const float* proj_b = (const float*)d_in[7];
    const float* ln1_g  = (const float*)d_in[8];
    const float* ln1_b  = (const float*)d_in[9];
    const float* mlp_w1 = (const float*)d_in[10];
    const float* mlp_b1 = (const float*)d_in[11];
    const float* mlp_w2 = (const float*)d_in[12];
    const float* mlp_b2 = (const float*)d_in[13];
    const float* ln2_g  = (const float*)d_in[14];
    const float* ln2_b  = (const float*)d_in[15];
    const float* head_w = (const float*)d_in[16];
    const float* head_b = (const float*)d_in[17];
    float* out = (float*)d_out;

    // ---- workspace budget / chunking ----
    const size_t perB =
        (size_t)N_ * D_ * 4 +        // h
        (size_t)N_ * D_ * 4 +        // q hi+lo
        (size_t)2 * N_ * D_ * 4 +    // kb+vb f32 (alias m hi+lo)
        (size_t)4 * D_ * N_ * 2 +    // kT/vT hi+lo
        (size_t)D_ * D_ * 4 +        // kv
        (size_t)2 * D_ * D_ * 2 +    // kv2t hi+lo
        (size_t)2 * N_ * 4 +         // mean,rstd
        4096;                        // dsum,pooled,align slop
    const size_t fixedW = 2ull * (576 * 192 + 384 * 192 + 192 * 384) * 2 + 65536;
    int BC = B_;
    while (BC > 1 && fixedW + (size_t)BC * perB > ws_size) BC >>= 1;
    const int nchunks = B_ / BC;
    const size_t rows = (size_t)BC * N_;

    // ---- bump allocator ----
    char* p = (char*)d_ws;
    auto alloc = [&](size_t bytes) -> char* {
        char* r = p;
        p += (bytes + 255) & ~(size_t)255;
        return r;
    };
    ushort_t* qw_hi = (ushort_t*)alloc(576 * 192 * 2);
    ushort_t* qw_lo = (ushort_t*)alloc(576 * 192 * 2);
    ushort_t* w1_hi = (ushort_t*)alloc(384 * 192 * 2);
    ushort_t* w1_lo = (ushort_t*)alloc(384 * 192 * 2);
    ushort_t* w2_hi = (ushort_t*)alloc(192 * 384 * 2);
    ushort_t* w2_lo = (ushort_t*)alloc(192 * 384 * 2);

    float*    h      = (float*)alloc(rows * D_ * 4);
    ushort_t* q_hi   = (ushort_t*)alloc(rows * D_ * 2);
    ushort_t* q_lo   = (ushort_t*)alloc(rows * D_ * 2);
    float*    kb     = (float*)alloc(rows * D_ * 4);
    float*    vb     = (float*)alloc(rows * D_ * 4);
    ushort_t* kT_hi  = (ushort_t*)alloc((size_t)BC * D_ * N_ * 2);
    ushort_t* kT_lo  = (ushort_t*)alloc((size_t)BC * D_ * N_ * 2);
    ushort_t* vT_hi  = (ushort_t*)alloc((size_t)BC * D_ * N_ * 2);
    ushort_t* vT_lo  = (ushort_t*)alloc((size_t)BC * D_ * N_ * 2);
    float*    kv     = (float*)alloc((size_t)BC * D_ * D_ * 4);
    ushort_t* kv2t_h = (ushort_t*)alloc((size_t)BC * D_ * D_ * 2);
    ushort_t* kv2t_l = (ushort_t*)alloc((size_t)BC * D_ * D_ * 2);
    float*    mean   = (float*)alloc(rows * 4);
    float*    rstd   = (float*)alloc(rows * 4);
    float*    dsum   = (float*)alloc((size_t)BC * 4);
    float*    pooled = (float*)alloc((size_t)BC * D_ * 4);
    ushort_t* m_hi   = (ushort_t*)kb;   // m [rows,H] split reuses kb,vb
    ushort_t* m_lo   = (ushort_t*)vb;

    // ---- weight pre-split (once per launch) ----
    splitw_k<<<(576 * 192 + 255) / 256, 256, 0, stream>>>(qkv_w, qw_hi, qw_lo, 576 * 192);
    splitw_k<<<(384 * 192 + 255) / 256, 256, 0, stream>>>(mlp_w1, w1_hi, w1_lo, 384 * 192);
    splitw_k<<<(192 * 384 + 255) / 256, 256, 0, stream>>>(mlp_w2, w2_hi, w2_lo, 192 * 384);

    const int gm = (int)(rows / 64);

    for (int ch = 0; ch < nchunks; ++ch) {
        const int b0 = ch * BC;
        const float* xc = x + (size_t)b0 * C_ * N_;

        hipMemsetAsync(dsum, 0, (size_t)BC * 4, stream);
        hipMemsetAsync(pooled, 0, (size_t)BC * D_ * 4, stream);
        hipMemsetAsync(kv, 0, (size_t)BC * D_ * D_ * 4, stream);

        // 1. patch embed
        conv_k<<<dim3(N_ / 64, BC), 192, 0, stream>>>(xc, conv_w, conv_b, pos, h);
        // 2. LN1 stats
        lnstats_k<<<rows / 4, 256, 0, stream>>>(h, mean, rstd);
        // 3. qkv (fused LN1; q split + qsum, k/v f32)
        mgemm<0, true, false><<<dim3(gm, 3), 256, 0, stream>>>(
            h, nullptr, nullptr, D_, qw_hi, qw_lo, ln1_g, ln1_b, mean, rstd,
            qkv_b, dsum, q_hi, q_lo, kb, vb, nullptr);
        // 4. transpose k,v -> split bf16
        transpose_k<<<dim3(N_ / 32, D_ / 32, BC * 2), 256, 0, stream>>>(
            kb, vb, kT_hi, kT_lo, vT_hi, vT_lo);
        // 5. kv = kT @ vT^T (batched, K-split 8, atomic accumulate)
        mgemm<4, false, true><<<dim3(BC * 3, 1, 8), 256, 0, stream>>>(
            nullptr, kT_hi, kT_lo, N_, vT_hi, vT_lo, nullptr, nullptr, nullptr, nullptr,
            nullptr, nullptr, nullptr, nullptr, kv, nullptr, nullptr);
        // 6. kv2T = proj_w @ kv^T -> split
        kv2_k<<<dim3(3, 3, BC), 256, 0, stream>>>(proj_w, kv, kv2t_h, kv2t_l);
        // 7. h += (q @ kv2) / (dsum+1e-6) + proj_b
        mgemm<3, false, true><<<dim3(gm, 1), 256, 0, stream>>>(
            nullptr, q_hi, q_lo, D_, kv2t_h, kv2t_l, nullptr, nullptr, nullptr, nullptr,
            proj_b, dsum, nullptr, nullptr, nullptr, nullptr, h);
        // 8. LN2 stats
        lnstats_k<<<rows / 4, 256, 0, stream>>>(h, mean, rstd);
        // 9. m = gelu(LN2(h) @ w1^T + b1) -> split
        mgemm<1, true, false><<<dim3(gm, 2), 256, 0, stream>>>(
            h, nullptr, nullptr, D_, w1_hi, w1_lo, ln2_g, ln2_b, mean, rstd,
            mlp_b1, nullptr, m_hi, m_lo, nullptr, nullptr, nullptr);
        // 10. h += m @ w2^T + b2
        mgemm<2, false, true><<<dim3(gm, 1), 256, 0, stream>>>(
            nullptr, m_hi, m_lo, H_, w2_hi, w2_lo, nullptr, nullptr, nullptr, nullptr,
            mlp_b2, nullptr, nullptr, nullptr, nullptr, nullptr, h);
        // 11. pool + head
        pool_k<<<dim3(N_ / 64, BC), 192, 0, stream>>>(h, pooled);
        head_k<<<BC, 192, 0, stream>>>(pooled, head_w, head_b, out + (size_t)b0 * NC_);
    }
}

// Round 5
// 1694.710 us; speedup vs baseline: 2.7873x; 1.2388x over previous
//
#include <hip/hip_runtime.h>
#include <cmath>

#define B_   128
#define C_   9
#define N_   2048
#define D_   192
#define H_   384
#define NC_  18

typedef unsigned short ushort_t;
typedef __attribute__((ext_vector_type(8))) __bf16 bf16x8;
typedef __attribute__((ext_vector_type(8))) short short8;
typedef __attribute__((ext_vector_type(16))) float f32x16;

__device__ __forceinline__ ushort_t f2bf(float x) {
    unsigned u = __float_as_uint(x);
    return (ushort_t)((u + 0x7fffu + ((u >> 16) & 1u)) >> 16);
}
__device__ __forceinline__ float bf2f(ushort_t h) {
    return __uint_as_float(((unsigned)h) << 16);
}
__device__ __forceinline__ bf16x8 ldfrag(const ushort_t* p) {
    short8 s = *(const short8*)p;
    return __builtin_bit_cast(bf16x8, s);
}

// ---------------------------------------------------------------------------
// conv1d(C->D,k=3,pad=1) + transpose + pos_embed -> h [BC*N, D] f32
// ---------------------------------------------------------------------------
__global__ __launch_bounds__(192) void conv_k(
    const float* __restrict__ x, const float* __restrict__ w,
    const float* __restrict__ cb, const float* __restrict__ pos,
    float* __restrict__ h)
{
    const int n0 = blockIdx.x * 64;
    const int b  = blockIdx.y;
    const int d  = threadIdx.x;

    __shared__ float xs[C_][66];
    for (int e = threadIdx.x; e < C_ * 66; e += 192) {
        int c = e / 66, i = e % 66;
        int n = n0 - 1 + i;
        xs[c][i] = (n >= 0 && n < N_) ? x[((size_t)b * C_ + c) * N_ + n] : 0.f;
    }
    float wr[C_][3];
#pragma unroll
    for (int c = 0; c < C_; ++c)
#pragma unroll
        for (int t = 0; t < 3; ++t) wr[c][t] = w[(d * C_ + c) * 3 + t];
    const float bias = cb[d];
    __syncthreads();
    for (int i = 0; i < 64; ++i) {
        int n = n0 + i;
        float acc = bias + pos[(size_t)n * D_ + d];
#pragma unroll
        for (int c = 0; c < C_; ++c)
#pragma unroll
            for (int t = 0; t < 3; ++t) acc += xs[c][i + t] * wr[c][t];
        h[((size_t)b * N_ + n) * D_ + d] = acc;
    }
}

// ---------------------------------------------------------------------------
// fused LayerNorm stats + normalize + hi/lo bf16 split. One wave per row.
// ---------------------------------------------------------------------------
__global__ __launch_bounds__(256) void lnsplit_k(
    const float* __restrict__ h, const float* __restrict__ g, const float* __restrict__ b,
    ushort_t* __restrict__ oh, ushort_t* __restrict__ ol)
{
    const int wid = threadIdx.x >> 6, lane = threadIdx.x & 63;
    const size_t row = (size_t)blockIdx.x * 4 + wid;
    const float* hr = h + row * D_;
    float v[3]; float s = 0.f, q = 0.f;
#pragma unroll
    for (int i = 0; i < 3; ++i) { v[i] = hr[lane + i * 64]; s += v[i]; q += v[i] * v[i]; }
#pragma unroll
    for (int o = 32; o > 0; o >>= 1) { s += __shfl_xor(s, o); q += __shfl_xor(q, o); }
    const float m = s * (1.f / D_);
    const float rs = rsqrtf(q * (1.f / D_) - m * m + 1e-5f);
#pragma unroll
    for (int i = 0; i < 3; ++i) {
        int c = lane + i * 64;
        float nv = (v[i] - m) * rs * g[c] + b[c];
        ushort_t hb = f2bf(nv);
        oh[row * D_ + c] = hb;
        ol[row * D_ + c] = f2bf(nv - bf2f(hb));
    }
}

// ---------------------------------------------------------------------------
// split f32 -> (hi,lo) bf16 planes (weights, once per launch)
// ---------------------------------------------------------------------------
__global__ __launch_bounds__(256) void splitw_k(
    const float* __restrict__ w, ushort_t* __restrict__ hi, ushort_t* __restrict__ lo, int n)
{
    int i = blockIdx.x * 256 + threadIdx.x;
    if (i < n) {
        float v = w[i];
        ushort_t hb = f2bf(v);
        hi[i] = hb;
        lo[i] = f2bf(v - bf2f(hb));
    }
}

// ---------------------------------------------------------------------------
// Split-bf16 MFMA GEMM, 2-phase pipelined with global_load_lds + LDS dbuf.
// C[m,n] = sum_k A[m,k]*W[n,k]; BN=192, BK=32, 256 thr = 4 waves (2x2).
// LDS per buffer: sAh[4koct][BM][8] sAl | sWh[4][192][8] sWl.
// EPI 0: qkv. by=0: q -> split + qsum->dsum; by=1/2: k/v -> TRANSPOSED split
//        (kT/vT [(b*192+d)][N]) via LDS bounce. relu on q,k.
// EPI 1: gelu -> split m (cols by*192..)
// EPI 2: facc += acc + bias
// EPI 3: facc += acc/(dsum[b]+1e-6) + bias, W batched per 2048 rows
// EPI 4: kv atomicAdd (A rows = b*192+d, W batched per 192 rows, K-split grid.z)
// ---------------------------------------------------------------------------
template <int EPI, int BM>
__global__ __launch_bounds__(256) void mgemm(
    const ushort_t* __restrict__ Ah, const ushort_t* __restrict__ Al, int K,
    const ushort_t* __restrict__ Wh, const ushort_t* __restrict__ Wl,
    const float* __restrict__ bias, float* __restrict__ dsum,
    ushort_t* __restrict__ oh, ushort_t* __restrict__ ol,
    ushort_t* __restrict__ kTh, ushort_t* __restrict__ kTl,
    ushort_t* __restrict__ vTh, ushort_t* __restrict__ vTl,
    float* __restrict__ facc)
{
    extern __shared__ ushort_t smem[];
    constexpr int MI   = BM / 64;          // m-frags per wave
    constexpr int BUFE = BM * 64 + 12288;  // elems per buffer
    constexpr int NCH  = 24 + 8 * MI;      // stage chunks per K-step

    const int tid  = threadIdx.x;
    const int lane = tid & 63;
    const int l5   = lane >> 5;
    const int wid  = tid >> 6;
    const int wr = wid >> 1, wc = wid & 1;
    const int bx = blockIdx.x, by = blockIdx.y;
    const int m0 = bx * BM;

    size_t wbase = 0;
    if (EPI == 0 || EPI == 1) wbase = (size_t)by * 192 * K;
    else if (EPI == 3) wbase = (size_t)(m0 >> 11) * D_ * D_;
    else if (EPI == 4) wbase = (size_t)(bx / 3) * 192 * (size_t)K;
    const ushort_t* Whp = Wh + wbase;
    const ushort_t* Wlp = Wl + wbase;

    int kbeg = 0, kend = K;
    if (EPI == 4) { int seg = K / gridDim.z; kbeg = blockIdx.z * seg; kend = kbeg + seg; }

    auto stage = [&](int buf, int k0) {
        const int base = buf * BUFE;
#pragma unroll
        for (int i = 0; i < NCH / 4; ++i) {
            int c = wid + i * 4;
            const ushort_t* src;
            int dst;
            if (c < 8 * MI) {
                int koct = c & 3, tt = c >> 2;
                int plane = tt & 1, rb = tt >> 1;
                const ushort_t* ap = plane ? Al : Ah;
                src = ap + (size_t)(m0 + rb * 64 + lane) * K + k0 + koct * 8;
                dst = plane * (BM * 32) + koct * (BM * 8) + rb * 512;
            } else {
                int c2 = c - 8 * MI;
                int koct = c2 & 3, tt = c2 >> 2;
                int plane = tt & 1, rb = tt >> 1;
                const ushort_t* wp = plane ? Wlp : Whp;
                src = wp + (size_t)(rb * 64 + lane) * K + k0 + koct * 8;
                dst = BM * 64 + plane * 6144 + koct * 1536 + rb * 512;
            }
            __builtin_amdgcn_global_load_lds(
                (const __attribute__((address_space(1))) void*)src,
                (__attribute__((address_space(3))) void*)(smem + base + dst),
                16, 0, 0);
        }
    };

    f32x16 acc[MI][3] = {};

    const int nt = (kend - kbeg) / 32;
    stage(0, kbeg);
    __syncthreads();
    int cur = 0;
    for (int t = 0; t < nt; ++t) {
        if (t + 1 < nt) stage(cur ^ 1, kbeg + (t + 1) * 32);
        const ushort_t* bb = smem + cur * BUFE;
#pragma unroll
        for (int kh = 0; kh < 2; ++kh) {
            bf16x8 ah[MI], al[MI];
#pragma unroll
            for (int mi = 0; mi < MI; ++mi) {
                int ao = (kh * 2 + l5) * (BM * 8) + (wr * (BM / 2) + mi * 32 + (lane & 31)) * 8;
                ah[mi] = ldfrag(bb + ao);
                al[mi] = ldfrag(bb + BM * 32 + ao);
            }
#pragma unroll
            for (int tn = 0; tn < 3; ++tn) {
                int wo = BM * 64 + (kh * 2 + l5) * 1536 + (wc * 96 + tn * 32 + (lane & 31)) * 8;
                bf16x8 wh = ldfrag(bb + wo);
                bf16x8 wl = ldfrag(bb + wo + 6144);
#pragma unroll
                for (int mi = 0; mi < MI; ++mi) {
                    acc[mi][tn] = __builtin_amdgcn_mfma_f32_32x32x16_bf16(ah[mi], wh, acc[mi][tn], 0, 0, 0);
                    acc[mi][tn] = __builtin_amdgcn_mfma_f32_32x32x16_bf16(ah[mi], wl, acc[mi][tn], 0, 0, 0);
                    acc[mi][tn] = __builtin_amdgcn_mfma_f32_32x32x16_bf16(al[mi], wh, acc[mi][tn], 0, 0, 0);
                }
            }
        }
        __syncthreads();
        cur ^= 1;
    }

    const int cb = wc * 96 + (lane & 31);

    if (EPI == 0) {
        if (by == 0) {
            float qsum = 0.f;
#pragma unroll
            for (int mi = 0; mi < MI; ++mi) {
                const int rb0 = m0 + wr * (BM / 2) + mi * 32 + 4 * l5;
#pragma unroll
                for (int tn = 0; tn < 3; ++tn) {
                    const int col = cb + tn * 32;
                    const float bv = bias[col];
#pragma unroll
                    for (int r = 0; r < 16; ++r) {
                        int row = rb0 + (r & 3) + 8 * (r >> 2);
                        float v = fmaxf(acc[mi][tn][r] + bv, 0.f);
                        qsum += v;
                        ushort_t hb = f2bf(v);
                        oh[(size_t)row * D_ + col] = hb;
                        ol[(size_t)row * D_ + col] = f2bf(v - bf2f(hb));
                    }
                }
            }
            __syncthreads();
            float* red = (float*)smem;
            red[tid] = qsum;
            __syncthreads();
            for (int o = 128; o > 0; o >>= 1) {
                if (tid < o) red[tid] += red[tid + o];
                __syncthreads();
            }
            if (tid == 0) atomicAdd(&dsum[m0 >> 11], red[0]);
        } else {
            // k/v: transpose via LDS bounce -> kT/vT [(b*192+d)][N] split bf16
            ushort_t* dsth = (by == 1) ? kTh : vTh;
            ushort_t* dstl = (by == 1) ? kTl : vTl;
            constexpr int STR = BM + 8;
#pragma unroll
            for (int plane = 0; plane < 2; ++plane) {
                __syncthreads();
#pragma unroll
                for (int mi = 0; mi < MI; ++mi) {
                    const int rl0 = wr * (BM / 2) + mi * 32 + 4 * l5;
#pragma unroll
                    for (int tn = 0; tn < 3; ++tn) {
                        const int col = cb + tn * 32;
                        const float bv = bias[by * 192 + col];
#pragma unroll
                        for (int r = 0; r < 16; ++r) {
                            int rowl = rl0 + (r & 3) + 8 * (r >> 2);
                            float v = acc[mi][tn][r] + bv;
                            if (by == 1) v = fmaxf(v, 0.f);
                            ushort_t hb = f2bf(v);
                            smem[col * STR + rowl] = plane ? f2bf(v - bf2f(hb)) : hb;
                        }
                    }
                }
                __syncthreads();
                if (tid < 192) {
                    ushort_t* dst = plane ? dstl : dsth;
                    size_t gbase = ((size_t)(m0 >> 11) * 192 + tid) * (size_t)N_ + (m0 & 2047);
#pragma unroll
                    for (int i2 = 0; i2 < BM / 8; ++i2)
                        *(uint4*)(dst + gbase + i2 * 8) = *(const uint4*)&smem[tid * STR + i2 * 8];
                }
            }
        }
    } else if (EPI == 1) {
#pragma unroll
        for (int mi = 0; mi < MI; ++mi) {
            const int rb0 = m0 + wr * (BM / 2) + mi * 32 + 4 * l5;
#pragma unroll
            for (int tn = 0; tn < 3; ++tn) {
                const int colg = by * 192 + cb + tn * 32;
                const float bv = bias[colg];
#pragma unroll
                for (int r = 0; r < 16; ++r) {
                    int row = rb0 + (r & 3) + 8 * (r >> 2);
                    float v = acc[mi][tn][r] + bv;
                    float gv = 0.5f * v * (1.f + erff(v * 0.70710678118654752f));
                    ushort_t hb = f2bf(gv);
                    oh[(size_t)row * H_ + colg] = hb;
                    ol[(size_t)row * H_ + colg] = f2bf(gv - bf2f(hb));
                }
            }
        }
    } else if (EPI == 2 || EPI == 3) {
        float s = 1.f;
        if (EPI == 3) s = 1.f / (dsum[m0 >> 11] + 1e-6f);
#pragma unroll
        for (int mi = 0; mi < MI; ++mi) {
            const int rb0 = m0 + wr * (BM / 2) + mi * 32 + 4 * l5;
#pragma unroll
            for (int tn = 0; tn < 3; ++tn) {
                const int col = cb + tn * 32;
                const float bv = bias[col];
#pragma unroll
                for (int r = 0; r < 16; ++r) {
                    int row = rb0 + (r & 3) + 8 * (r >> 2);
                    facc[(size_t)row * D_ + col] += acc[mi][tn][r] * s + bv;
                }
            }
        }
    } else if (EPI == 4) {
#pragma unroll
        for (int mi = 0; mi < MI; ++mi) {
            const int rb0 = m0 + wr * (BM / 2) + mi * 32 + 4 * l5;
#pragma unroll
            for (int tn = 0; tn < 3; ++tn) {
                const int col = cb + tn * 32;
#pragma unroll
                for (int r = 0; r < 16; ++r) {
                    int row = rb0 + (r & 3) + 8 * (r >> 2);
                    atomicAdd(&facc[(size_t)row * D_ + col], acc[mi][tn][r]);
                }
            }
        }
    }
}

// ---------------------------------------------------------------------------
// kv2T[b,e,d] = sum_f proj_w[e,f]*kv[b,d,f]  -> split bf16 output (tiny)
// ---------------------------------------------------------------------------
__global__ __launch_bounds__(256) void kv2_k(
    const float* __restrict__ pw, const float* __restrict__ kv,
    ushort_t* __restrict__ oh, ushort_t* __restrict__ ol)
{
    __shared__ float As[16][68];
    __shared__ float Ws[16][68];
    const int tid = threadIdx.x;
    const int tx = tid & 15, ty = tid >> 4;
    const int m0 = blockIdx.x * 64;   // e
    const int n0 = blockIdx.y * 64;   // d
    const int b = blockIdx.z;
    const float* kvb = kv + (size_t)b * D_ * D_;
    const int lm = tid >> 2;
    const int lk = (tid & 3) * 4;

    float acc[4][4] = {};
    for (int k0 = 0; k0 < D_; k0 += 16) {
        float4 av = *(const float4*)(pw + (size_t)(m0 + lm) * D_ + k0 + lk);
        As[lk + 0][lm] = av.x; As[lk + 1][lm] = av.y;
        As[lk + 2][lm] = av.z; As[lk + 3][lm] = av.w;
        float4 wv = *(const float4*)(kvb + (size_t)(n0 + lm) * D_ + k0 + lk);
        Ws[lk + 0][lm] = wv.x; Ws[lk + 1][lm] = wv.y;
        Ws[lk + 2][lm] = wv.z; Ws[lk + 3][lm] = wv.w;
        __syncthreads();
#pragma unroll
        for (int kk = 0; kk < 16; ++kk) {
            float4 a4 = *(const float4*)&As[kk][ty * 4];
            float4 w4 = *(const float4*)&Ws[kk][tx * 4];
            float a[4] = {a4.x, a4.y, a4.z, a4.w};
            float w[4] = {w4.x, w4.y, w4.z, w4.w};
#pragma unroll
            for (int i = 0; i < 4; ++i)
#pragma unroll
                for (int j = 0; j < 4; ++j) acc[i][j] += a[i] * w[j];
        }
        __syncthreads();
    }
#pragma unroll
    for (int i = 0; i < 4; ++i) {
        ushort_t hb[4], lb[4];
#pragma unroll
        for (int j = 0; j < 4; ++j) {
            float v = acc[i][j];
            hb[j] = f2bf(v);
            lb[j] = f2bf(v - bf2f(hb[j]));
        }
        size_t base = (size_t)b * D_ * D_ + (size_t)(m0 + ty * 4 + i) * D_ + n0 + tx * 4;
        *(uint2*)&oh[base] = make_uint2((unsigned)hb[0] | ((unsigned)hb[1] << 16),
                                        (unsigned)hb[2] | ((unsigned)hb[3] << 16));
        *(uint2*)&ol[base] = make_uint2((unsigned)lb[0] | ((unsigned)lb[1] << 16),
                                        (unsigned)lb[2] | ((unsigned)lb[3] << 16));
    }
}

// ---------------------------------------------------------------------------
__global__ __launch_bounds__(192) void pool_k(
    const float* __restrict__ h, float* __restrict__ pooled)
{
    const int n0 = blockIdx.x * 64;
    const int b  = blockIdx.y;
    const int d  = threadIdx.x;
    const float* hb = h + ((size_t)b * N_ + n0) * D_;
    float s = 0.f;
#pragma unroll 8
    for (int i = 0; i < 64; ++i) s += hb[(size_t)i * D_ + d];
    atomicAdd(pooled + (size_t)b * D_ + d, s);
}

__global__ __launch_bounds__(192) void head_k(
    const float* __restrict__ pooled, const float* __restrict__ hw,
    const float* __restrict__ hb, float* __restrict__ out)
{
    const int b = blockIdx.x, d = threadIdx.x;
    __shared__ float p[D_];
    p[d] = pooled[(size_t)b * D_ + d] * (1.f / N_);
    __syncthreads();
    if (d < NC_) {
        float acc = hb[d];
        for (int e = 0; e < D_; ++e) acc += p[e] * hw[d * D_ + e];
        out[b * NC_ + d] = acc;
    }
}

// ---------------------------------------------------------------------------
extern "C" void kernel_launch(void* const* d_in, const int* in_sizes, int n_in,
                              void* d_out, int out_size, void* d_ws, size_t ws_size,
                              hipStream_t stream) {
    (void)in_sizes; (void)n_in; (void)out_size;

    const float* x      = (const float*)d_in[0];
    const float* conv_w = (const float*)d_in[1];
    const float* conv_b = (const float*)d_in[2];
    const float* pos    = (const float*)d_in[3];
    const float* qkv_w  = (const float*)d_in[4];
    const float* qkv_b  = (const float*)d_in[5];
    const float* proj_w = (const float*)d_in[6];
    const float* proj_b = (const float*)d_in[7];
    const float* ln1_g  = (const float*)d_in[8];
    const float* ln1_b  = (const float*)d_in[9];
    const float* mlp_w1 = (const float*)d_in[10];
    const float* mlp_b1 = (const float*)d_in[11];
    const float* mlp_w2 = (const float*)d_in[12];
    const float* mlp_b2 = (const float*)d_in[13];
    const float* ln2_g  = (const float*)d_in[14];
    const float* ln2_b  = (const float*)d_in[15];
    const float* head_w = (const float*)d_in[16];
    const float* head_b = (const float*)d_in[17];
    float* out = (float*)d_out;

    // ---- chunk sizing ----
    // per batch el: h f32 (1.5M) + hn/q/kT/vT split planes + kv + kv2t + small
    const size_t perB =
        (size_t)N_ * D_ * 4 +            // h
        (size_t)N_ * D_ * 2 * 2 +        // hn hi+lo
        (size_t)N_ * D_ * 2 * 2 +        // q hi+lo
        (size_t)N_ * D_ * 2 * 4 +        // kT,vT hi+lo
        (size_t)D_ * D_ * 4 +            // kv
        (size_t)D_ * D_ * 2 * 2 +        // kv2t hi+lo
        8192;                            // dsum,pooled,slop
    const size_t fixedW = 2ull * (576 * 192 + 384 * 192 + 192 * 384) * 2 + 65536;
    int BC = B_;
    while (BC > 1 && fixedW + (size_t)BC * perB > ws_size) BC >>= 1;
    const int nchunks = B_ / BC;
    const size_t rows = (size_t)BC * N_;

    char* p = (char*)d_ws;
    auto alloc = [&](size_t bytes) -> char* {
        char* r = p;
        p += (bytes + 255) & ~(size_t)255;
        return r;
    };
    ushort_t* qw_hi = (ushort_t*)alloc(576 * 192 * 2);
    ushort_t* qw_lo = (ushort_t*)alloc(576 * 192 * 2);
    ushort_t* w1_hi = (ushort_t*)alloc(384 * 192 * 2);
    ushort_t* w1_lo = (ushort_t*)alloc(384 * 192 * 2);
    ushort_t* w2_hi = (ushort_t*)alloc(192 * 384 * 2);
    ushort_t* w2_lo = (ushort_t*)alloc(192 * 384 * 2);

    const size_t szPl = rows * D_ * 2;            // one split plane (bytes)
    float*    h      = (float*)alloc(rows * D_ * 4);
    ushort_t* hn_hi  = (ushort_t*)alloc(szPl);
    ushort_t* hn_lo  = (ushort_t*)alloc(szPl);
    ushort_t* q_hi   = (ushort_t*)alloc(szPl);
    ushort_t* q_lo   = (ushort_t*)alloc(szPl);
    ushort_t* kT_hi  = (ushort_t*)alloc(szPl);
    ushort_t* kT_lo  = (ushort_t*)alloc(szPl);
    ushort_t* vT_hi  = (ushort_t*)alloc(szPl);
    ushort_t* vT_lo  = (ushort_t*)alloc(szPl);
    float*    kv     = (float*)alloc((size_t)BC * D_ * D_ * 4);
    ushort_t* kv2t_h = (ushort_t*)alloc((size_t)BC * D_ * D_ * 2);
    ushort_t* kv2t_l = (ushort_t*)alloc((size_t)BC * D_ * D_ * 2);
    float*    dsum   = (float*)alloc((size_t)BC * 4);
    float*    pooled = (float*)alloc((size_t)BC * D_ * 4);
    ushort_t* m_hi   = kT_hi;   // m [rows,H] hi spans kT_hi+kT_lo (contiguous)
    ushort_t* m_lo   = vT_hi;   // m lo spans vT_hi+vT_lo

    splitw_k<<<(576 * 192 + 255) / 256, 256, 0, stream>>>(qkv_w, qw_hi, qw_lo, 576 * 192);
    splitw_k<<<(384 * 192 + 255) / 256, 256, 0, stream>>>(mlp_w1, w1_hi, w1_lo, 384 * 192);
    splitw_k<<<(192 * 384 + 255) / 256, 256, 0, stream>>>(mlp_w2, w2_hi, w2_lo, 192 * 384);

    const int gm = (int)(rows / 128);
    const size_t SH128 = (size_t)(128 * 64 + 12288) * 2 * 2;  // 81920 B
    const size_t SH64  = (size_t)(64 * 64 + 12288) * 2 * 2;   // 65536 B

    for (int ch = 0; ch < nchunks; ++ch) {
        const int b0 = ch * BC;
        const float* xc = x + (size_t)b0 * C_ * N_;

        hipMemsetAsync(dsum, 0, (size_t)BC * 4, stream);
        hipMemsetAsync(pooled, 0, (size_t)BC * D_ * 4, stream);
        hipMemsetAsync(kv, 0, (size_t)BC * D_ * D_ * 4, stream);

        // 1. patch embed
        conv_k<<<dim3(N_ / 64, BC), 192, 0, stream>>>(xc, conv_w, conv_b, pos, h);
        // 2. LN1 + split
        lnsplit_k<<<rows / 4, 256, 0, stream>>>(h, ln1_g, ln1_b, hn_hi, hn_lo);
        // 3. qkv: q split + qsum; k,v transposed split
        mgemm<0, 128><<<dim3(gm, 3), 256, SH128, stream>>>(
            hn_hi, hn_lo, D_, qw_hi, qw_lo, qkv_b, dsum,
            q_hi, q_lo, kT_hi, kT_lo, vT_hi, vT_lo, nullptr);
        // 4. kv = k^T v (batched, K=N, K-split 8, atomic)
        mgemm<4, 64><<<dim3(BC * 3, 1, 8), 256, SH64, stream>>>(
            kT_hi, kT_lo, N_, vT_hi, vT_lo, nullptr, nullptr,
            nullptr, nullptr, nullptr, nullptr, nullptr, nullptr, kv);
        // 5. kv2T = proj_w @ kv^T -> split
        kv2_k<<<dim3(3, 3, BC), 256, 0, stream>>>(proj_w, kv, kv2t_h, kv2t_l);
        // 6. h += (q @ kv2) / (dsum+1e-6) + proj_b
        mgemm<3, 128><<<dim3(gm, 1), 256, SH128, stream>>>(
            q_hi, q_lo, D_, kv2t_h, kv2t_l, proj_b, dsum,
            nullptr, nullptr, nullptr, nullptr, nullptr, nullptr, h);
        // 7. LN2 + split
        lnsplit_k<<<rows / 4, 256, 0, stream>>>(h, ln2_g, ln2_b, hn_hi, hn_lo);
        // 8. m = gelu(hn @ w1^T + b1) -> split
        mgemm<1, 128><<<dim3(gm, 2), 256, SH128, stream>>>(
            hn_hi, hn_lo, D_, w1_hi, w1_lo, mlp_b1, nullptr,
            m_hi, m_lo, nullptr, nullptr, nullptr, nullptr, nullptr);
        // 9. h += m @ w2^T + b2
        mgemm<2, 128><<<dim3(gm, 1), 256, SH128, stream>>>(
            m_hi, m_lo, H_, w2_hi, w2_lo, mlp_b2, nullptr,
            nullptr, nullptr, nullptr, nullptr, nullptr, nullptr, h);
        // 10. pool + head
        pool_k<<<dim3(N_ / 64, BC), 192, 0, stream>>>(h, pooled);
        head_k<<<BC, 192, 0, stream>>>(pooled, head_w, head_b, out + (size_t)b0 * NC_);
    }
}